// Round 3
// baseline (214.466 us; speedup 1.0000x reference)
//
#include <hip/hip_runtime.h>
#include <hip/hip_bf16.h>

// GraphSAGE: out = normalize( [x, segsum(vals*x[cols], rows)] @ W^T + b )
// N=100000, E=1600000, IN_F=128, OUT_F=128.
//
// ws layout:
//   [0    , ~400K)  row_ptr (int[N+1])
//   [448K , 512K)   Wf: fragment-major bf16 W, 4096 x 16B
//   [640K , +25.6M) xb: bf16(x), N x 128 (rows of 16 uint4)
//   [next , +25.6M) nb: neighbor bf16, N x 128

typedef __bf16 bf16x8_t __attribute__((ext_vector_type(8)));
typedef float f32x4_t __attribute__((ext_vector_type(4)));
typedef float f32x2_t __attribute__((ext_vector_type(2)));

__device__ __forceinline__ unsigned int f32_to_bf16(float f) {
    unsigned int u = __float_as_uint(f);
    unsigned int r = u + 0x7fffu + ((u >> 16) & 1u);   // RNE (no NaN inputs)
    return r >> 16;
}
__device__ __forceinline__ unsigned int pack2(float a, float b) {
    return f32_to_bf16(a) | (f32_to_bf16(b) << 16);
}
__device__ __forceinline__ float bflo(unsigned int p) { return __uint_as_float(p << 16); }
__device__ __forceinline__ float bfhi(unsigned int p) { return __uint_as_float(p & 0xffff0000u); }

// --- K0: fused prep: xcast | rowptr | wcast (block-range split) ------------
// xcast item i (< N*16): xb4[i] = bf16 of x[ row i/16, feats 8*(i%16)..+8 ]
// Wf[(t*8+ks)*64+lane] = bf16x8 of W[t*16+(lane&15)][ks*32+(lane>>4)*8 ..+8]
__global__ void prep_kernel(const float* __restrict__ x, uint4* __restrict__ xb4,
                            const int* __restrict__ rows, int* __restrict__ row_ptr,
                            const float* __restrict__ W, uint4* __restrict__ Wf,
                            int Nn, int Ee, int xcast_blks, int rowptr_blks) {
    int blk = blockIdx.x;
    if (blk < xcast_blks) {
        int i = blk * 256 + threadIdx.x;
        if (i < Nn * 16) {
            const float4* xf = (const float4*)x;
            float4 f0 = xf[(size_t)i * 2];
            float4 f1 = xf[(size_t)i * 2 + 1];
            uint4 o;
            o.x = pack2(f0.x, f0.y); o.y = pack2(f0.z, f0.w);
            o.z = pack2(f1.x, f1.y); o.w = pack2(f1.z, f1.w);
            xb4[i] = o;
        }
    } else if (blk < xcast_blks + rowptr_blks) {
        int n = (blk - xcast_blks) * 256 + threadIdx.x;
        if (n <= Nn) {
            int lo = 0, hi = Ee;
            while (lo < hi) {
                int mid = (lo + hi) >> 1;
                if (rows[mid] < n) lo = mid + 1; else hi = mid;
            }
            row_ptr[n] = lo;
        }
    } else {
        int i = (blk - xcast_blks - rowptr_blks) * 256 + threadIdx.x;  // 0..4095
        int lane = i & 63, ks = (i >> 6) & 7, t = i >> 9;
        int row = t * 16 + (lane & 15);
        int col = ks * 32 + (lane >> 4) * 8;
        const float* p = W + (size_t)row * 256 + col;
        uint4 o;
        o.x = pack2(p[0], p[1]); o.y = pack2(p[2], p[3]);
        o.z = pack2(p[4], p[5]); o.w = pack2(p[6], p[7]);
        Wf[i] = o;
    }
}

// --- K1: nb[n,:] = sum_{e in row n} vals[e] * xb[cols[e],:] ----------------
// wave = 4 nodes; slot h=lane>>4 owns node h, 16 lanes x 16B cover one row.
// 2 edges in flight per slot; exhausted slots exec-masked. No reductions.
__global__ __launch_bounds__(256, 8) void agg_kernel(
        const int* __restrict__ row_ptr, const int* __restrict__ cols,
        const float* __restrict__ vals, const char* __restrict__ xb,
        uint4* __restrict__ nb, int Nn) {
    int lane = threadIdx.x & 63;
    int wave = threadIdx.x >> 6;
    int h = lane >> 4;           // node slot within wave
    int l = lane & 15;           // feature chunk: feats [8l, 8l+8)
    int n = (blockIdx.x * 4 + wave) * 4 + h;
    bool valid = n < Nn;
    int nn = valid ? n : Nn - 1;
    int start = row_ptr[nn], end = row_ptr[nn + 1];
    if (!valid) end = start;     // masked slots do no work
    unsigned loff = (unsigned)l << 4;

    f32x2_t a0 = {0.f, 0.f}, a1 = {0.f, 0.f}, a2 = {0.f, 0.f}, a3 = {0.f, 0.f};

#define EDGE(E, C, V)                                              \
    {                                                              \
        int q = max(min((E), end - 1), 0);                         \
        C = cols[q];                                               \
        V = ((E) < end) ? vals[q] : 0.f;                           \
    }
#define ACC(P, V)                                                  \
    {                                                              \
        f32x2_t vv = {(V), (V)};                                   \
        f32x2_t t0 = {bflo((P).x), bfhi((P).x)};                   \
        f32x2_t t1 = {bflo((P).y), bfhi((P).y)};                   \
        f32x2_t t2 = {bflo((P).z), bfhi((P).z)};                   \
        f32x2_t t3 = {bflo((P).w), bfhi((P).w)};                   \
        a0 += vv * t0; a1 += vv * t1; a2 += vv * t2; a3 += vv * t3;\
    }

    int e = start;
    int c0 = 0, c1 = 0; float v0 = 0.f, v1 = 0.f;
    if (e < end) { EDGE(e, c0, v0); EDGE(e + 1, c1, v1); }
    while (e < end) {
        int e2 = e + 2;
        int d0 = 0, d1 = 0; float w0 = 0.f, w1 = 0.f;
        if (e2 < end) { EDGE(e2, d0, w0); EDGE(e2 + 1, d1, w1); }
        uint4 p0 = *(const uint4*)(xb + (((unsigned)c0 << 8) | loff));
        uint4 p1 = *(const uint4*)(xb + (((unsigned)c1 << 8) | loff));
        ACC(p0, v0);
        ACC(p1, v1);
        c0 = d0; v0 = w0; c1 = d1; v1 = w1;
        e = e2;
    }
#undef EDGE
#undef ACC

    if (valid) {
        uint4 o;
        o.x = pack2(a0.x, a0.y); o.y = pack2(a1.x, a1.y);
        o.z = pack2(a2.x, a2.y); o.w = pack2(a3.x, a3.y);
        nb[(size_t)n * 16 + l] = o;
    }
}

// --- K2: out = normalize([xb, nb] @ W^T + b) -------------------------------
// block = 256 = 4 waves; wave: 32 rows (2 sets of 16) x 128 cols, K=256.
// Each B fragment (coalesced, fragment-major Wf) feeds 2 MFMAs.
// C/D: col = lane&15 (+16*t), row = (lane>>4)*4 + reg   [m89 layout]
__global__ __launch_bounds__(256, 3) void gemm_norm_kernel(
        const unsigned short* __restrict__ xb, const unsigned short* __restrict__ nb,
        const bf16x8_t* __restrict__ Wf, const float* __restrict__ b,
        float* __restrict__ out, int Nn) {
    int lane = threadIdx.x & 63;
    int wave = threadIdx.x >> 6;
    int m    = lane & 15;
    int quad = lane >> 4;
    int r0   = (blockIdx.x * 4 + wave) * 32;

    int arow0 = min(r0 + m, Nn - 1);
    int arow1 = min(r0 + 16 + m, Nn - 1);
    const bf16x8_t* Ax0 = (const bf16x8_t*)(xb + (size_t)arow0 * 128);
    const bf16x8_t* An0 = (const bf16x8_t*)(nb + (size_t)arow0 * 128);
    const bf16x8_t* Ax1 = (const bf16x8_t*)(xb + (size_t)arow1 * 128);
    const bf16x8_t* An1 = (const bf16x8_t*)(nb + (size_t)arow1 * 128);

    bf16x8_t a0[8], a1[8];
#pragma unroll
    for (int ks = 0; ks < 4; ++ks) {
        a0[ks]     = Ax0[ks * 4 + quad];
        a0[4 + ks] = An0[ks * 4 + quad];
        a1[ks]     = Ax1[ks * 4 + quad];
        a1[4 + ks] = An1[ks * 4 + quad];
    }

    f32x4_t acc0[8], acc1[8];
#pragma unroll
    for (int t = 0; t < 8; ++t) {
        acc0[t] = (f32x4_t){0.f, 0.f, 0.f, 0.f};
        acc1[t] = (f32x4_t){0.f, 0.f, 0.f, 0.f};
    }

#pragma unroll
    for (int t = 0; t < 8; ++t) {
#pragma unroll
        for (int ks = 0; ks < 8; ++ks) {
            bf16x8_t B = Wf[(t * 8 + ks) * 64 + lane];
            acc0[t] = __builtin_amdgcn_mfma_f32_16x16x32_bf16(a0[ks], B, acc0[t], 0, 0, 0);
            acc1[t] = __builtin_amdgcn_mfma_f32_16x16x32_bf16(a1[ks], B, acc1[t], 0, 0, 0);
        }
    }

    float bc[8];
#pragma unroll
    for (int t = 0; t < 8; ++t) bc[t] = b[t * 16 + m];

    float sq0[4] = {0.f, 0.f, 0.f, 0.f}, sq1[4] = {0.f, 0.f, 0.f, 0.f};
#pragma unroll
    for (int t = 0; t < 8; ++t)
#pragma unroll
        for (int r = 0; r < 4; ++r) {
            float u0 = acc0[t][r] + bc[t];
            float u1 = acc1[t][r] + bc[t];
            sq0[r] += u0 * u0;
            sq1[r] += u1 * u1;
        }
#pragma unroll
    for (int off = 1; off <= 8; off <<= 1) {
#pragma unroll
        for (int r = 0; r < 4; ++r) {
            sq0[r] += __shfl_xor(sq0[r], off, 64);
            sq1[r] += __shfl_xor(sq1[r], off, 64);
        }
    }
    float sc0[4], sc1[4];
#pragma unroll
    for (int r = 0; r < 4; ++r) {
        sc0[r] = 1.f / fmaxf(sqrtf(sq0[r]), 1e-12f);
        sc1[r] = 1.f / fmaxf(sqrtf(sq1[r]), 1e-12f);
    }

#pragma unroll
    for (int r = 0; r < 4; ++r) {
        int row0 = r0 + quad * 4 + r;
        int row1 = r0 + 16 + quad * 4 + r;
        if (row0 < Nn) {
            float* orow = out + (size_t)row0 * 128;
#pragma unroll
            for (int t = 0; t < 8; ++t) orow[t * 16 + m] = (acc0[t][r] + bc[t]) * sc0[r];
        }
        if (row1 < Nn) {
            float* orow = out + (size_t)row1 * 128;
#pragma unroll
            for (int t = 0; t < 8; ++t) orow[t * 16 + m] = (acc1[t][r] + bc[t]) * sc1[r];
        }
    }
}

extern "C" void kernel_launch(void* const* d_in, const int* in_sizes, int n_in,
                              void* d_out, int out_size, void* d_ws, size_t ws_size,
                              hipStream_t stream) {
    const float* x    = (const float*)d_in[0];
    const int*   rows = (const int*)  d_in[1];
    const int*   cols = (const int*)  d_in[2];
    const float* vals = (const float*)d_in[3];
    const float* W    = (const float*)d_in[4];
    const float* b    = (const float*)d_in[5];
    float*       out  = (float*)d_out;

    const int Nn = in_sizes[0] / 128;    // 100000
    const int Ee = in_sizes[1];          // 1600000

    char*  ws      = (char*)d_ws;
    int*   row_ptr = (int*)ws;
    uint4* Wf      = (uint4*)(ws + 448 * 1024);
    uint4* xb      = (uint4*)(ws + 640 * 1024);
    uint4* nb      = (uint4*)(ws + 640 * 1024 + (size_t)Nn * 256);

    const int xcast_blks  = (Nn * 16 + 255) / 256;   // 6250
    const int rowptr_blks = (Nn + 1 + 255) / 256;    // 391
    const int wcast_blks  = 16;

    prep_kernel<<<xcast_blks + rowptr_blks + wcast_blks, 256, 0, stream>>>(
        x, xb, rows, row_ptr, W, Wf, Nn, Ee, xcast_blks, rowptr_blks);
    agg_kernel<<<(Nn + 15) / 16, 256, 0, stream>>>(
        row_ptr, cols, vals, (const char*)xb, nb, Nn);
    gemm_norm_kernel<<<(Nn + 127) / 128, 256, 0, stream>>>(
        (const unsigned short*)xb, (const unsigned short*)nb,
        (const bf16x8_t*)Wf, b, out, Nn);
}

// Round 4
// 196.981 us; speedup vs baseline: 1.0888x; 1.0888x over previous
//
#include <hip/hip_runtime.h>
#include <hip/hip_bf16.h>

// GraphSAGE: out = normalize( [x, segsum(vals*x[cols], rows)] @ W^T + b )
// N=100000, E=1600000, IN_F=128, OUT_F=128.
//
// Round 4: fused agg+gemm+norm (one kernel, 16 nodes/block, nb lives in LDS);
// 4 gathers in flight per node-slot (latency-bound phase, warm-L3 replay at
// same dur proved BW headroom).
//
// ws layout:
//   [0    , ~400K)  row_ptr (int[N+1])
//   [448K , 512K)   Wf: fragment-major bf16 W, 4096 x 16B
//   [640K , +25.6M) xb: bf16(x), N x 128 (rows of 16 uint4)

typedef __bf16 bf16x8_t __attribute__((ext_vector_type(8)));
typedef float f32x4_t __attribute__((ext_vector_type(4)));
typedef float f32x2_t __attribute__((ext_vector_type(2)));

__device__ __forceinline__ unsigned int f32_to_bf16(float f) {
    unsigned int u = __float_as_uint(f);
    unsigned int r = u + 0x7fffu + ((u >> 16) & 1u);   // RNE (no NaN inputs)
    return r >> 16;
}
__device__ __forceinline__ unsigned int pack2(float a, float b) {
    return f32_to_bf16(a) | (f32_to_bf16(b) << 16);
}
__device__ __forceinline__ float bflo(unsigned int p) { return __uint_as_float(p << 16); }
__device__ __forceinline__ float bfhi(unsigned int p) { return __uint_as_float(p & 0xffff0000u); }

// --- K0: fused prep: xcast | rowptr | wcast (block-range split) ------------
__global__ void prep_kernel(const float* __restrict__ x, uint4* __restrict__ xb4,
                            const int* __restrict__ rows, int* __restrict__ row_ptr,
                            const float* __restrict__ W, uint4* __restrict__ Wf,
                            int Nn, int Ee, int xcast_blks, int rowptr_blks) {
    int blk = blockIdx.x;
    if (blk < xcast_blks) {
        int i = blk * 256 + threadIdx.x;
        if (i < Nn * 16) {
            const float4* xf = (const float4*)x;
            float4 f0 = xf[(size_t)i * 2];
            float4 f1 = xf[(size_t)i * 2 + 1];
            uint4 o;
            o.x = pack2(f0.x, f0.y); o.y = pack2(f0.z, f0.w);
            o.z = pack2(f1.x, f1.y); o.w = pack2(f1.z, f1.w);
            xb4[i] = o;
        }
    } else if (blk < xcast_blks + rowptr_blks) {
        int n = (blk - xcast_blks) * 256 + threadIdx.x;
        if (n <= Nn) {
            int lo = 0, hi = Ee;
            while (lo < hi) {
                int mid = (lo + hi) >> 1;
                if (rows[mid] < n) lo = mid + 1; else hi = mid;
            }
            row_ptr[n] = lo;
        }
    } else {
        int i = (blk - xcast_blks - rowptr_blks) * 256 + threadIdx.x;  // 0..4095
        int lane = i & 63, ks = (i >> 6) & 7, t = i >> 9;
        int row = t * 16 + (lane & 15);
        int col = ks * 32 + (lane >> 4) * 8;
        const float* p = W + (size_t)row * 256 + col;
        uint4 o;
        o.x = pack2(p[0], p[1]); o.y = pack2(p[2], p[3]);
        o.z = pack2(p[4], p[5]); o.w = pack2(p[6], p[7]);
        Wf[i] = o;
    }
}

// --- K1: fused agg + gemm + normalize --------------------------------------
// block = 256 thr = 4 waves, 16 nodes (grid 6250 exact).
// Phase 1 (agg): wave w, slot h=lane>>4 owns node w*4+h; 16 lanes x 16B
//   cover one 256B xb row; 4 edges in flight per slot; fp32 accum ->
//   bf16 to LDS (node-stride 17*16B: 2-way banks max = free).
// Phase 2 (gemm): 16 rows, K=256 (self half from global xb, neighbor half
//   from LDS), 8 col-tiles split 2/wave; MFMA 16x16x32 bf16; cross-wave
//   norm reduction through 256B LDS; fused bias+normalize store.
__global__ void fused_kernel(const int* __restrict__ row_ptr,
                             const int* __restrict__ cols,
                             const float* __restrict__ vals,
                             const char* __restrict__ xbB,
                             const bf16x8_t* __restrict__ Wf,
                             const float* __restrict__ b,
                             float* __restrict__ out, int Nn) {
    __shared__ uint4 nbLDS[16 * 17];
    __shared__ float __attribute__((aligned(16))) sqLDS[16][4];

    int lane = threadIdx.x & 63;
    int w    = threadIdx.x >> 6;

    // ---------------- phase 1: aggregate ----------------
    {
        int h = lane >> 4;            // node slot within wave
        int l = lane & 15;            // feature chunk [8l, 8l+8)
        int node = w * 4 + h;         // 0..15
        int n = blockIdx.x * 16 + node;
        int nn = min(n, Nn - 1);
        int start = row_ptr[nn], end = row_ptr[nn + 1];
        if (n >= Nn) end = start;
        unsigned loff = (unsigned)l << 4;

        f32x2_t a0 = {0.f, 0.f}, a1 = {0.f, 0.f}, a2 = {0.f, 0.f}, a3 = {0.f, 0.f};

#define EDGE4(E, C0, C1, C2, C3, V0, V1, V2, V3)                                \
        {                                                                       \
            int q0 = min((E), end - 1),     q1 = min((E) + 1, end - 1);         \
            int q2 = min((E) + 2, end - 1), q3 = min((E) + 3, end - 1);         \
            C0 = cols[q0]; C1 = cols[q1]; C2 = cols[q2]; C3 = cols[q3];         \
            V0 = ((E)     < end) ? vals[q0] : 0.f;                              \
            V1 = ((E) + 1 < end) ? vals[q1] : 0.f;                              \
            V2 = ((E) + 2 < end) ? vals[q2] : 0.f;                              \
            V3 = ((E) + 3 < end) ? vals[q3] : 0.f;                              \
        }
#define ACC(P, V)                                                               \
        {                                                                       \
            f32x2_t vv = {(V), (V)};                                            \
            f32x2_t t0 = {bflo((P).x), bfhi((P).x)};                            \
            f32x2_t t1 = {bflo((P).y), bfhi((P).y)};                            \
            f32x2_t t2 = {bflo((P).z), bfhi((P).z)};                            \
            f32x2_t t3 = {bflo((P).w), bfhi((P).w)};                            \
            a0 += vv * t0; a1 += vv * t1; a2 += vv * t2; a3 += vv * t3;         \
        }

        int e = start;
        int c0 = 0, c1 = 0, c2 = 0, c3 = 0;
        float v0 = 0.f, v1 = 0.f, v2 = 0.f, v3 = 0.f;
        if (e < end) EDGE4(e, c0, c1, c2, c3, v0, v1, v2, v3);
        while (e < end) {
            int en = e + 4;
            int d0 = 0, d1 = 0, d2 = 0, d3 = 0;
            float w0 = 0.f, w1 = 0.f, w2 = 0.f, w3 = 0.f;
            if (en < end) EDGE4(en, d0, d1, d2, d3, w0, w1, w2, w3);
            uint4 p0 = *(const uint4*)(xbB + (((unsigned)c0 << 8) | loff));
            uint4 p1 = *(const uint4*)(xbB + (((unsigned)c1 << 8) | loff));
            uint4 p2 = *(const uint4*)(xbB + (((unsigned)c2 << 8) | loff));
            uint4 p3 = *(const uint4*)(xbB + (((unsigned)c3 << 8) | loff));
            ACC(p0, v0); ACC(p1, v1); ACC(p2, v2); ACC(p3, v3);
            c0 = d0; c1 = d1; c2 = d2; c3 = d3;
            v0 = w0; v1 = w1; v2 = w2; v3 = w3;
            e = en;
        }
#undef EDGE4
#undef ACC

        uint4 o;
        o.x = pack2(a0.x, a0.y); o.y = pack2(a1.x, a1.y);
        o.z = pack2(a2.x, a2.y); o.w = pack2(a3.x, a3.y);
        nbLDS[node * 17 + l] = o;      // bank = (4*node + 4*l) % 32 -> 2-way max
    }
    __syncthreads();

    // ---------------- phase 2: gemm + normalize ----------------
    int m    = lane & 15;
    int quad = lane >> 4;
    int r0   = blockIdx.x * 16;

    int arow = min(r0 + m, Nn - 1);
    const bf16x8_t* Ax = (const bf16x8_t*)(xbB + (size_t)arow * 256);

    bf16x8_t a[8];
#pragma unroll
    for (int ks = 0; ks < 4; ++ks) a[ks] = Ax[ks * 4 + quad];
#pragma unroll
    for (int ks = 0; ks < 4; ++ks)
        a[4 + ks] = *(const bf16x8_t*)&nbLDS[m * 17 + ks * 4 + quad];

    f32x4_t acc[2];
    float bc[2];
#pragma unroll
    for (int j = 0; j < 2; ++j) {
        int t = w * 2 + j;
        acc[j] = (f32x4_t){0.f, 0.f, 0.f, 0.f};
        bc[j]  = b[t * 16 + m];
#pragma unroll
        for (int ks = 0; ks < 8; ++ks) {
            acc[j] = __builtin_amdgcn_mfma_f32_16x16x32_bf16(
                a[ks], Wf[(t * 8 + ks) * 64 + lane], acc[j], 0, 0, 0);
        }
    }

    // per-row sum of squares: lane holds rows quad*4+r, cols (w*2+j)*16+m
    float sq[4] = {0.f, 0.f, 0.f, 0.f};
#pragma unroll
    for (int j = 0; j < 2; ++j)
#pragma unroll
        for (int r = 0; r < 4; ++r) {
            float u = acc[j][r] + bc[j];
            sq[r] += u * u;
        }
#pragma unroll
    for (int off = 1; off <= 8; off <<= 1) {
#pragma unroll
        for (int r = 0; r < 4; ++r) sq[r] += __shfl_xor(sq[r], off, 64);
    }
    if (m == 0) {
#pragma unroll
        for (int r = 0; r < 4; ++r) sqLDS[quad * 4 + r][w] = sq[r];
    }
    __syncthreads();

    float scale[4];
#pragma unroll
    for (int r = 0; r < 4; ++r) {
        const float4 q4 = *(const float4*)sqLDS[quad * 4 + r];
        float tot = q4.x + q4.y + q4.z + q4.w;
        scale[r] = 1.f / fmaxf(sqrtf(tot), 1e-12f);
    }

#pragma unroll
    for (int r = 0; r < 4; ++r) {
        int row = r0 + quad * 4 + r;
        if (row < Nn) {
            float* orow = out + (size_t)row * 128;
#pragma unroll
            for (int j = 0; j < 2; ++j) {
                int t = w * 2 + j;
                orow[t * 16 + m] = (acc[j][r] + bc[j]) * scale[r];
            }
        }
    }
}

extern "C" void kernel_launch(void* const* d_in, const int* in_sizes, int n_in,
                              void* d_out, int out_size, void* d_ws, size_t ws_size,
                              hipStream_t stream) {
    const float* x    = (const float*)d_in[0];
    const int*   rows = (const int*)  d_in[1];
    const int*   cols = (const int*)  d_in[2];
    const float* vals = (const float*)d_in[3];
    const float* W    = (const float*)d_in[4];
    const float* b    = (const float*)d_in[5];
    float*       out  = (float*)d_out;

    const int Nn = in_sizes[0] / 128;    // 100000
    const int Ee = in_sizes[1];          // 1600000

    char*  ws      = (char*)d_ws;
    int*   row_ptr = (int*)ws;
    uint4* Wf      = (uint4*)(ws + 448 * 1024);
    uint4* xb      = (uint4*)(ws + 640 * 1024);

    const int xcast_blks  = (Nn * 16 + 255) / 256;   // 6250
    const int rowptr_blks = (Nn + 1 + 255) / 256;    // 391
    const int wcast_blks  = 16;

    prep_kernel<<<xcast_blks + rowptr_blks + wcast_blks, 256, 0, stream>>>(
        x, xb, rows, row_ptr, W, Wf, Nn, Ee, xcast_blks, rowptr_blks);
    fused_kernel<<<(Nn + 15) / 16, 256, 0, stream>>>(
        row_ptr, cols, vals, (const char*)xb,
        (const bf16x8_t*)Wf, b, out, Nn);
}